// Round 25
// baseline (210.136 us; speedup 1.0000x reference)
//
#include <hip/hip_runtime.h>
#include <hip/hip_fp16.h>
#include <math.h>

#define TSZ2 4096
#define RMAXF 2.0f
#define NBAS 10
#define HID 100
#define CHK 1536   // edges per binning block (small blocks => TLP)
#define SCT 256    // scat1/hist threads
#define KN 8       // nodes per wave in k_aggupd

__device__ __forceinline__ float sigmoidf_(float z) { return 1.0f / (1.0f + __expf(-z)); }

// ---------------- fused: blocks [0,nblk) = bucket histogram + p0 ; blocks [nblk,..) = radial table ----------------
__launch_bounds__(256)
__global__ void k_hist(const int* __restrict__ edst, int* __restrict__ bcnt, int E, int nblk, int nbuck,
                       const float* __restrict__ x0, const float* __restrict__ P0l,
                       __half* __restrict__ p0, int N,
                       const float* __restrict__ w1, const float* __restrict__ b1,
                       const float* __restrict__ w2, __half* __restrict__ tbh) {
    int tid = threadIdx.x;
    if ((int)blockIdx.x < nblk) {
        __shared__ int lb[512];
        int blk = blockIdx.x;
        lb[tid] = 0; lb[tid + 256] = 0;
        __syncthreads();
        int e0 = blk * CHK;
        #pragma unroll
        for (int k = 0; k < CHK / SCT; ++k) {
            int e = e0 + k * SCT + tid;
            if (e < E) atomicAdd(&lb[edst[e] >> 7], 1);
        }
        // fused p0 = x0 @ P0[0]
        for (int i = blk * SCT + tid; i < N * 16; i += nblk * SCT) {
            int n = i >> 4, m = i & 15;
            float acc = 0.0f;
            #pragma unroll
            for (int c = 0; c < 16; ++c) acc += x0[n * 16 + c] * P0l[c * 16 + m];
            p0[i] = __float2half(acc);
        }
        __syncthreads();
        for (int b = tid; b < nbuck; b += 256) bcnt[(size_t)b * nblk + blk] = lb[b];
    } else {
        // radial table (only w0: first 16 MLP outputs), fp16 [l][t][c]
        int tb = blockIdx.x - nblk;
        int l = tb >> 7;
        int t0 = (tb & 127) * 32;
        __shared__ float emb[32][NBAS];
        __shared__ float h[32][HID];
        __shared__ float w2s[HID * 16];
        for (int i = tid; i < HID * 16; i += 256) {
            int k = i >> 4, j = i & 15;
            w2s[i] = w2[l * HID * 48 + k * 48 + j];
        }
        for (int i = tid; i < 32 * NBAS; i += 256) {
            int tt = i / NBAS, bi = i % NBAS;
            float r = (16.0f * (t0 + tt) + 7.5f) * (RMAXF / 65535.0f);
            float d = (r - (bi + 0.5f) * 0.2f) * 5.0f;
            emb[tt][bi] = (fabsf(d) < 1.0f) ? cosf(1.5707963267948966f * d) * 3.1622776601683795f : 0.0f;
        }
        __syncthreads();
        for (int i = tid; i < 32 * HID; i += 256) {
            int tt = i / HID, hh = i % HID;
            float z = b1[l * HID + hh];
            #pragma unroll
            for (int bi = 0; bi < NBAS; ++bi) z += emb[tt][bi] * w1[(l * NBAS + bi) * HID + hh];
            h[tt][hh] = z * sigmoidf_(z);
        }
        __syncthreads();
        for (int i = tid; i < 32 * 16; i += 256) {
            int tt = i >> 4, j = i & 15;
            int t = t0 + tt;
            float o = 0.0f;
            if (t != TSZ2 - 1) {   // last row stays zero = sentinel
                for (int k = 0; k < HID; ++k) o += h[tt][k] * w2s[k * 16 + j];
            }
            tbh[((size_t)l * TSZ2 + t) * 16 + j] = __float2half(o);
        }
    }
}

// ---------------- scan A: per-1024-chunk sums ----------------
__global__ void k_scanA(const int* __restrict__ bcnt, int* __restrict__ bsum, int M) {
    __shared__ int red[256];
    int base = blockIdx.x * 1024;
    int t = threadIdx.x;
    int s = 0;
    #pragma unroll
    for (int k = 0; k < 4; ++k) {
        int i = base + k * 256 + t;
        if (i < M) s += bcnt[i];
    }
    red[t] = s;
    __syncthreads();
    for (int off = 128; off > 0; off >>= 1) {
        if (t < off) red[t] += red[t + off];
        __syncthreads();
    }
    if (t == 0) bsum[blockIdx.x] = red[0];
}

// ---------------- scan C (merged with B): per-block prefix of bsum + apply; zero outacc ----------------
__global__ void k_scanC(const int* __restrict__ bcnt, const int* __restrict__ bsum,
                        int* __restrict__ bofs, int* __restrict__ bbase,
                        int M, int nblk, int nbuck, int E,
                        unsigned long long* __restrict__ outacc) {
    __shared__ int red[256];
    __shared__ int part[256];
    int b = blockIdx.x, t = threadIdx.x;
    if (b == 0 && t == 0) *outacc = 0ull;
    // prefix over bsum[0..b)
    int s0 = 0;
    for (int i = t; i < b; i += 256) s0 += bsum[i];
    red[t] = s0;
    __syncthreads();
    for (int off = 128; off > 0; off >>= 1) {
        if (t < off) red[t] += red[t + off];
        __syncthreads();
    }
    int boff = red[0];
    int base = b * 1024;
    int v[4];
    int s = 0;
    #pragma unroll
    for (int k = 0; k < 4; ++k) {
        int i = base + t * 4 + k;
        v[k] = (i < M) ? bcnt[i] : 0;
        s += v[k];
    }
    part[t] = s;
    __syncthreads();
    for (int off = 1; off < 256; off <<= 1) {
        int x = (t >= off) ? part[t - off] : 0;
        __syncthreads();
        part[t] += x;
        __syncthreads();
    }
    int run = boff + ((t == 0) ? 0 : part[t - 1]);
    #pragma unroll
    for (int k = 0; k < 4; ++k) {
        int i = base + t * 4 + k;
        if (i < M) {
            int bucket = i / nblk;
            int blk = i - bucket * nblk;
            bofs[(size_t)blk * nbuck + bucket] = run;
            if (blk == 0) bbase[bucket] = run;
            run += v[k];
        }
    }
    if (b == 0 && t == 0) bbase[nbuck] = E;
}

// ---------------- phase 1: LDS-staged scatter, SoA bins, coalesced write-out ----------------
__launch_bounds__(256)
__global__ void k_scat1(const float* __restrict__ pos, const int* __restrict__ esrc,
                        const int* __restrict__ edst, const int* __restrict__ bofs,
                        uint2* __restrict__ bbuf, int E, int nbuck) {
    __shared__ int lcnt[512];
    __shared__ int lcur[512];
    __shared__ int delta[512];
    __shared__ unsigned binx[CHK];   // SoA: 4B random LDS writes (fewer bank conflicts)
    __shared__ unsigned biny[CHK];
    int tid = threadIdx.x;
    int blk = blockIdx.x;
    lcnt[tid] = 0; lcnt[tid + 256] = 0;
    __syncthreads();
    int e0 = blk * CHK;
    int nloc = min(CHK, E - e0);
    // pass 1: geometry into registers + bucket counts
    uint2 ent[CHK / SCT];
    int bkt[CHK / SCT];
    #pragma unroll
    for (int k = 0; k < CHK / SCT; ++k) {
        int i = k * SCT + tid;
        bkt[k] = -1;
        if (i < nloc) {
            int e = e0 + i;
            int s = esrc[e], d = edst[e];
            float vx = pos[s * 3 + 0] - pos[d * 3 + 0];
            float vy = pos[s * 3 + 1] - pos[d * 3 + 1];
            float vz = pos[s * 3 + 2] - pos[d * 3 + 2];
            float r = sqrtf(vx * vx + vy * vy + vz * vz);
            unsigned rtfix = (unsigned)fminf(r * (65535.0f / RMAXF) + 0.5f, 65535.0f);
            ent[k].x = (unsigned)s | (rtfix << 16);
            ent[k].y = (unsigned)d;
            bkt[k] = d >> 7;
            atomicAdd(&lcnt[bkt[k]], 1);
        }
    }
    __syncthreads();
    // inclusive scan of lcnt over 512 entries, 2 per thread
    lcur[tid] = lcnt[tid];
    lcur[tid + 256] = lcnt[tid + 256];
    __syncthreads();
    for (int off = 1; off < 512; off <<= 1) {
        int v0 = (tid >= off) ? lcur[tid - off] : 0;
        int v1 = (tid + 256 >= off) ? lcur[tid + 256 - off] : 0;
        __syncthreads();
        if (tid >= off) lcur[tid] += v0;
        if (tid + 256 >= off) lcur[tid + 256] += v1;
        __syncthreads();
    }
    #pragma unroll
    for (int q = 0; q < 2; ++q) {
        int b = q * 256 + tid;
        int ex = lcur[b] - lcnt[b];    // exclusive local offset
        delta[b] = ((b < nbuck) ? bofs[(size_t)blk * nbuck + b] : 0) - ex;
        lcnt[b] = ex;                  // reuse lcnt as placement cursor
    }
    __syncthreads();
    // pass 2: place entries into LDS bins
    #pragma unroll
    for (int k = 0; k < CHK / SCT; ++k) {
        if (bkt[k] >= 0) {
            int slot = atomicAdd(&lcnt[bkt[k]], 1);
            binx[slot] = ent[k].x;
            biny[slot] = ent[k].y;
        }
    }
    __syncthreads();
    // pass 3: coalesced write-out (consecutive i in a bucket run -> consecutive global addr)
    #pragma unroll
    for (int k = 0; k < CHK / SCT; ++k) {
        int i = k * SCT + tid;
        if (i < nloc) {
            uint2 v;
            v.x = binx[i];
            v.y = biny[i];
            int b = ((int)v.y) >> 7;
            bbuf[delta[b] + i] = v;
        }
    }
}

// ---------------- phase 2: bucket counting-sort -> padded CSR(4B) + rowinfo + padfill ----------------
__global__ void k_scat2(const uint2* __restrict__ bbuf, const int* __restrict__ bbase,
                        unsigned* __restrict__ csr, int2* __restrict__ rowinfo, int N) {
    int b = blockIdx.x;
    int tid = threadIdx.x;
    __shared__ int cnt128[128];
    __shared__ int base128[128];
    __shared__ int cur[128];
    __shared__ int part[128];
    if (tid < 128) cnt128[tid] = 0;
    __syncthreads();
    int j0 = bbase[b], j1 = bbase[b + 1];
    int n0 = b << 7;
    for (int j = j0 + tid; j < j1; j += 256)
        atomicAdd(&cnt128[((int)bbuf[j].y) & 127], 1);
    __syncthreads();
    if (tid < 128) part[tid] = (cnt128[tid] + 3) & ~3;
    __syncthreads();
    for (int off = 1; off < 128; off <<= 1) {
        int v = 0;
        if (tid < 128 && tid >= off) v = part[tid - off];
        __syncthreads();
        if (tid < 128) part[tid] += v;
        __syncthreads();
    }
    int pbase = j0 + 512 * b;   // padded base: bbase[b] + per-bucket pad slack
    if (tid < 128) {
        int ex = pbase + ((tid == 0) ? 0 : part[tid - 1]);
        base128[tid] = ex;
        cur[tid] = ex;
        int n = n0 + tid;
        if (n < N) rowinfo[n] = make_int2(ex, (cnt128[tid] + 3) & ~3);
    }
    __syncthreads();
    for (int j = j0 + tid; j < j1; j += 256) {
        uint2 e = bbuf[j];
        int local = ((int)e.y) & 127;
        int slot = atomicAdd(&cur[local], 1);
        csr[slot] = e.x;
    }
    __syncthreads();
    // sentinel padfill (<=3 per node): rtfix=0xFFFF -> table row 4095 = zeros
    if (tid < 128) {
        int end = base128[tid] + ((cnt128[tid] + 3) & ~3);
        for (int s = cur[tid]; s < end; ++s) csr[s] = 0xFFFF0000u;
    }
}

// ---------------- fused aggregation + node update; KN nodes/wave, one DMA drain ----------------
// wp0==1: write x0n + p0out (layers 0,1). wp0==0: final layer -> fused output reduction
__launch_bounds__(256)
__global__ void k_aggupd(const int2* __restrict__ rowinfo,
                         const unsigned* __restrict__ csr,
                         const __half* __restrict__ tbh, const __half* __restrict__ p0g,
                         const float* __restrict__ x0c,
                         float* __restrict__ x0n, __half* __restrict__ p0out,
                         const float* __restrict__ Wsc, const float* __restrict__ Wa,
                         const float* __restrict__ P0n, const float* __restrict__ Wout,
                         unsigned long long* __restrict__ outacc,
                         int N, int wp0) {
    const float INVS = 0.17677669529663687f;  // 1/sqrt(32)
    __shared__ unsigned ROW[4][KN][96];   // KN nodes/wave, 64-edge window + prefetch slack
    int tid = threadIdx.x;
    int wid = tid >> 6;
    int lane = tid & 63;
    int n0 = blockIdx.x * (4 * KN) + wid * KN;
    if (n0 >= N) return;
    int g = lane >> 4, c = lane & 15;
    // rowinfo for the KN-aligned group as int4 loads
    int e0s[KN], pls[KN];
    #pragma unroll
    for (int q = 0; q < KN / 2; ++q) {
        int4 rr = ((const int4*)rowinfo)[(n0 >> 1) + q];
        e0s[2 * q] = rr.x; pls[2 * q] = rr.y;
        e0s[2 * q + 1] = rr.z; pls[2 * q + 1] = rr.w;
    }
    #pragma unroll
    for (int i = 0; i < KN; ++i) if (n0 + i >= N) pls[i] = 0;
    // issue all DMAs, one drain
    #pragma unroll
    for (int i = 0; i < KN; ++i) {
        if (pls[i] > 0)
            __builtin_amdgcn_global_load_lds(
                (const __attribute__((address_space(1))) void*)(csr + e0s[i] + lane),
                (__attribute__((address_space(3))) void*)(&ROW[wid][i][0]), 4, 0, 0);
    }
    // x0 rows for all nodes (issued before the drain to overlap)
    float xr[KN];
    #pragma unroll
    for (int i = 0; i < KN; ++i) xr[i] = 0.0f;
    if (lane < 16) {
        #pragma unroll
        for (int i = 0; i < KN; ++i)
            if (n0 + i < N) xr[i] = x0c[(size_t)(n0 + i) * 16 + lane];
    }
    asm volatile("s_waitcnt vmcnt(0)" ::: "memory");
    float wsum = 0.0f;   // fused output accumulator (final layer)
    #pragma unroll
    for (int i = 0; i < KN; ++i) {
        int n = n0 + i;
        if (n >= N) break;
        int e0 = e0s[i];
        int plen = pls[i];
        float xr0 = xr[i];
        float a0 = 0.0f;
        if (plen > 0) {
            const unsigned* RB = &ROW[wid][i][0];
            int L = plen >> 2;               // pad-4 rows: exact group count
            int Lm = L < 16 ? L : 16;        // LDS window covers 64 edges
            unsigned c0 = RB[g], c1 = RB[4 + g], c2v = RB[8 + g], c3 = RB[12 + g];
            float p0v = __half2float(p0g[(c0 & 0xffffu) * 16 + c]);
            float w0v = __half2float(tbh[(c0 >> 20) * 16 + c]);
            float p1v = __half2float(p0g[(c1 & 0xffffu) * 16 + c]);
            float w1v = __half2float(tbh[(c1 >> 20) * 16 + c]);
            float p2v = __half2float(p0g[(c2v & 0xffffu) * 16 + c]);
            float w2v = __half2float(tbh[(c2v >> 20) * 16 + c]);
            float p3v = __half2float(p0g[(c3 & 0xffffu) * 16 + c]);
            float w3v = __half2float(tbh[(c3 >> 20) * 16 + c]);
            #pragma unroll 2
            for (int k = 0; k < Lm; ++k) {
                unsigned c4 = RB[(k + 4) * 4 + g];      // max idx 91 < 96
                float p4v = __half2float(p0g[(c4 & 0xffffu) * 16 + c]);
                float w4v = __half2float(tbh[(c4 >> 20) * 16 + c]);
                a0 += w0v * p0v;
                c0 = c1; c1 = c2v; c2v = c3; c3 = c4;
                p0v = p1v; w0v = w1v;
                p1v = p2v; w1v = w2v;
                p2v = p3v; w2v = w3v;
                p3v = p4v; w3v = w4v;
            }
            if (plen > 64) {   // rare fallback beyond LDS window (Poisson(32): ~never)
                for (int j = e0 + 64 + g; j < e0 + plen; j += 4) {
                    unsigned cx = csr[j];
                    a0 += __half2float(tbh[(cx >> 20) * 16 + c]) *
                          __half2float(p0g[(cx & 0xffffu) * 16 + c]);
                }
            }
        }
        // reduce over the 4 edge slots (lane bits 4,5); lane&15 = channel
        a0 += __shfl_xor(a0, 16);
        a0 += __shfl_xor(a0, 32);
        a0 *= INVS;
        // tail: s_j = sum_cc x0[cc]*Wsc[cc*48+j] + agg0[cc]*Wa[cc*48+j] (j=c; only first 16 live)
        float sj = 0.0f;
        #pragma unroll
        for (int t = 0; t < 4; ++t) {
            int cc = g * 4 + t;
            float xv = __shfl(xr0, cc);
            float av = __shfl(a0, cc);
            sj += xv * Wsc[cc * 48 + c] + av * Wa[cc * 48 + c];
        }
        sj += __shfl_xor(sj, 16);
        sj += __shfl_xor(sj, 32);
        float act = sj * sigmoidf_(sj);
        if (wp0) {
            if (lane < 16) x0n[(size_t)n * 16 + lane] = act;
            float pn = 0.0f;
            #pragma unroll
            for (int t = 0; t < 4; ++t) {
                int cc = g * 4 + t;
                float av = __shfl(act, cc);
                pn += av * P0n[cc * 16 + c];
            }
            pn += __shfl_xor(pn, 16);
            pn += __shfl_xor(pn, 32);
            if (lane < 16) p0out[(size_t)n * 16 + lane] = __float2half(pn);
        } else {
            // final layer: node_out = sum_c act[c]*Wout[c]; reduce over lanes 0..15
            float v = (lane < 16) ? act * Wout[c] : 0.0f;
            v += __shfl_xor(v, 1);
            v += __shfl_xor(v, 2);
            v += __shfl_xor(v, 4);
            v += __shfl_xor(v, 8);
            if (lane == 0) wsum += v;
        }
    }
    if (!wp0 && lane == 0) {
        long long q = (long long)llrintf(wsum * 1048576.0f);   // 2^20 fixed point (deterministic int atomics)
        atomicAdd(outacc, (unsigned long long)q);
    }
}

// ---------------- final convert: fixed-point accumulator -> float output ----------------
__global__ void k_out2(const unsigned long long* __restrict__ outacc, float* __restrict__ out,
                       float scale) {
    long long q = (long long)(*outacc);
    out[0] = (float)((double)q * (1.0 / 1048576.0) * (double)scale);
}

extern "C" void kernel_launch(void* const* d_in, const int* in_sizes, int n_in,
                              void* d_out, int out_size, void* d_ws, size_t ws_size,
                              hipStream_t stream) {
    const float* pos = (const float*)d_in[0];
    const float* x   = (const float*)d_in[1];
    const int* esrc  = (const int*)d_in[2];
    const int* edst  = (const int*)d_in[3];
    const float* mlp_w1 = (const float*)d_in[5];
    const float* mlp_b1 = (const float*)d_in[6];
    const float* mlp_w2 = (const float*)d_in[7];
    const float* P0  = (const float*)d_in[8];
    const float* Wsc = (const float*)d_in[9];
    const float* Wa  = (const float*)d_in[10];
    const float* Wout = (const float*)d_in[13];
    int N = in_sizes[0] / 3;
    int E = in_sizes[2];
    int nbuck = (N + 127) >> 7;
    int nblk = (E + CHK - 1) / CHK;
    int M = nbuck * nblk;
    int cap = E + 512 * nbuck + 256;
    int nscan = (M + 1023) / 1024;

    char* ws = (char*)d_ws;
    size_t off = 0;
    auto alloc = [&](size_t bytes) -> void* {
        void* p = ws + off;
        off += (bytes + 255) & ~(size_t)255;
        return p;
    };
    int2*     rowinfo   = (int2*)alloc((size_t)(N + KN) * 8);
    int*      bbase     = (int*)alloc(513 * 4);
    int*      bsum      = (int*)alloc(512 * 4);
    unsigned long long* outacc = (unsigned long long*)alloc(256);
    int*      bcnt      = (int*)alloc((size_t)M * 4);
    int*      bofs      = (int*)alloc((size_t)M * 4);
    unsigned* csr       = (unsigned*)alloc((size_t)cap * 4);
    __half*   tbh       = (__half*)alloc((size_t)3 * TSZ2 * 16 * 2);
    __half*   p0A = (__half*)alloc((size_t)65536 * 16 * 2);   // src is 16-bit: index-safe
    __half*   p0B = (__half*)alloc((size_t)65536 * 16 * 2);
    float*    x0A = (float*)alloc((size_t)N * 16 * 4);
    float*    x0B = (float*)alloc((size_t)N * 16 * 4);
    uint2*    bbuf = (uint2*)alloc((size_t)E * 8);

    k_hist<<<nblk + 3 * (TSZ2 / 32), 256, 0, stream>>>(edst, bcnt, E, nblk, nbuck, x, P0, p0A, N,
                                                       mlp_w1, mlp_b1, mlp_w2, tbh);
    k_scanA<<<nscan, 256, 0, stream>>>(bcnt, bsum, M);
    k_scanC<<<nscan, 256, 0, stream>>>(bcnt, bsum, bofs, bbase, M, nblk, nbuck, E, outacc);
    k_scat1<<<nblk, SCT, 0, stream>>>(pos, esrc, edst, bofs, bbuf, E, nbuck);
    k_scat2<<<nbuck, 256, 0, stream>>>(bbuf, bbase, csr, rowinfo, N);

    float* x0bufs[2] = {x0A, x0B};
    __half* p0bufs[2] = {p0A, p0B};
    int npb = 4 * KN;   // nodes per block
    for (int l = 0; l < 3; ++l) {
        const float* x0c = (l == 0) ? x : x0bufs[l & 1];
        float* x0n = x0bufs[(l & 1) ^ 1];
        const __half* p0c = p0bufs[l & 1];
        __half* p0n = p0bufs[(l & 1) ^ 1];
        const float* P0next = (l < 2) ? (P0 + (l + 1) * 256) : P0;
        k_aggupd<<<(N + npb - 1) / npb, 256, 0, stream>>>(
            rowinfo, csr, tbh + (size_t)l * TSZ2 * 16, p0c,
            x0c, x0n, p0n,
            Wsc + l * 768, Wa + l * 768, P0next, Wout, outacc, N, (l < 2) ? 1 : 0);
    }
    float scale = (float)(1.0 / sqrt((double)N));
    k_out2<<<1, 1, 0, stream>>>(outacc, (float*)d_out, scale);
}

// Round 26
// 138.999 us; speedup vs baseline: 1.5118x; 1.5118x over previous
//
#include <hip/hip_runtime.h>
#include <hip/hip_fp16.h>
#include <math.h>

#define TSZ2 4096
#define RMAXF 2.0f
#define NBAS 10
#define HID 100
#define CHK 1536   // edges per binning block (small blocks => TLP)
#define SCT 256    // scat1/hist threads

__device__ __forceinline__ float sigmoidf_(float z) { return 1.0f / (1.0f + __expf(-z)); }

// ---------------- fused: blocks [0,nblk) = bucket histogram + p0 ; blocks [nblk,..) = radial table ----------------
__launch_bounds__(256)
__global__ void k_hist(const int* __restrict__ edst, int* __restrict__ bcnt, int E, int nblk, int nbuck,
                       const float* __restrict__ x0, const float* __restrict__ P0l,
                       __half* __restrict__ p0, int N,
                       const float* __restrict__ w1, const float* __restrict__ b1,
                       const float* __restrict__ w2, __half* __restrict__ tbh) {
    int tid = threadIdx.x;
    if ((int)blockIdx.x < nblk) {
        __shared__ int lb[512];
        int blk = blockIdx.x;
        lb[tid] = 0; lb[tid + 256] = 0;
        __syncthreads();
        int e0 = blk * CHK;
        #pragma unroll
        for (int k = 0; k < CHK / SCT; ++k) {
            int e = e0 + k * SCT + tid;
            if (e < E) atomicAdd(&lb[edst[e] >> 7], 1);
        }
        // fused p0 = x0 @ P0[0]
        for (int i = blk * SCT + tid; i < N * 16; i += nblk * SCT) {
            int n = i >> 4, m = i & 15;
            float acc = 0.0f;
            #pragma unroll
            for (int c = 0; c < 16; ++c) acc += x0[n * 16 + c] * P0l[c * 16 + m];
            p0[i] = __float2half(acc);
        }
        __syncthreads();
        for (int b = tid; b < nbuck; b += 256) bcnt[(size_t)b * nblk + blk] = lb[b];
    } else {
        // radial table (only w0: first 16 MLP outputs), fp16 [l][t][c]
        int tb = blockIdx.x - nblk;
        int l = tb >> 7;
        int t0 = (tb & 127) * 32;
        __shared__ float emb[32][NBAS];
        __shared__ float h[32][HID];
        __shared__ float w2s[HID * 16];
        for (int i = tid; i < HID * 16; i += 256) {
            int k = i >> 4, j = i & 15;
            w2s[i] = w2[l * HID * 48 + k * 48 + j];
        }
        for (int i = tid; i < 32 * NBAS; i += 256) {
            int tt = i / NBAS, bi = i % NBAS;
            float r = (16.0f * (t0 + tt) + 7.5f) * (RMAXF / 65535.0f);
            float d = (r - (bi + 0.5f) * 0.2f) * 5.0f;
            emb[tt][bi] = (fabsf(d) < 1.0f) ? cosf(1.5707963267948966f * d) * 3.1622776601683795f : 0.0f;
        }
        __syncthreads();
        for (int i = tid; i < 32 * HID; i += 256) {
            int tt = i / HID, hh = i % HID;
            float z = b1[l * HID + hh];
            #pragma unroll
            for (int bi = 0; bi < NBAS; ++bi) z += emb[tt][bi] * w1[(l * NBAS + bi) * HID + hh];
            h[tt][hh] = z * sigmoidf_(z);
        }
        __syncthreads();
        for (int i = tid; i < 32 * 16; i += 256) {
            int tt = i >> 4, j = i & 15;
            int t = t0 + tt;
            float o = 0.0f;
            if (t != TSZ2 - 1) {   // last row stays zero = sentinel
                for (int k = 0; k < HID; ++k) o += h[tt][k] * w2s[k * 16 + j];
            }
            tbh[((size_t)l * TSZ2 + t) * 16 + j] = __float2half(o);
        }
    }
}

// ---------------- scan A: per-1024-chunk sums ----------------
__global__ void k_scanA(const int* __restrict__ bcnt, int* __restrict__ bsum, int M) {
    __shared__ int red[256];
    int base = blockIdx.x * 1024;
    int t = threadIdx.x;
    int s = 0;
    #pragma unroll
    for (int k = 0; k < 4; ++k) {
        int i = base + k * 256 + t;
        if (i < M) s += bcnt[i];
    }
    red[t] = s;
    __syncthreads();
    for (int off = 128; off > 0; off >>= 1) {
        if (t < off) red[t] += red[t + off];
        __syncthreads();
    }
    if (t == 0) bsum[blockIdx.x] = red[0];
}

// ---------------- scan C (merged with B): per-block prefix of bsum + apply ----------------
__global__ void k_scanC(const int* __restrict__ bcnt, const int* __restrict__ bsum,
                        int* __restrict__ bofs, int* __restrict__ bbase,
                        int M, int nblk, int nbuck, int E) {
    __shared__ int red[256];
    __shared__ int part[256];
    int b = blockIdx.x, t = threadIdx.x;
    // prefix over bsum[0..b)
    int s0 = 0;
    for (int i = t; i < b; i += 256) s0 += bsum[i];
    red[t] = s0;
    __syncthreads();
    for (int off = 128; off > 0; off >>= 1) {
        if (t < off) red[t] += red[t + off];
        __syncthreads();
    }
    int boff = red[0];
    int base = b * 1024;
    int v[4];
    int s = 0;
    #pragma unroll
    for (int k = 0; k < 4; ++k) {
        int i = base + t * 4 + k;
        v[k] = (i < M) ? bcnt[i] : 0;
        s += v[k];
    }
    part[t] = s;
    __syncthreads();
    for (int off = 1; off < 256; off <<= 1) {
        int x = (t >= off) ? part[t - off] : 0;
        __syncthreads();
        part[t] += x;
        __syncthreads();
    }
    int run = boff + ((t == 0) ? 0 : part[t - 1]);
    #pragma unroll
    for (int k = 0; k < 4; ++k) {
        int i = base + t * 4 + k;
        if (i < M) {
            int bucket = i / nblk;
            int blk = i - bucket * nblk;
            bofs[(size_t)blk * nbuck + bucket] = run;
            if (blk == 0) bbase[bucket] = run;
            run += v[k];
        }
    }
    if (b == 0 && t == 0) bbase[nbuck] = E;
}

// ---------------- phase 1: LDS-staged scatter, SoA bins, coalesced write-out ----------------
__launch_bounds__(256)
__global__ void k_scat1(const float* __restrict__ pos, const int* __restrict__ esrc,
                        const int* __restrict__ edst, const int* __restrict__ bofs,
                        uint2* __restrict__ bbuf, int E, int nbuck) {
    __shared__ int lcnt[512];
    __shared__ int lcur[512];
    __shared__ int delta[512];
    __shared__ unsigned binx[CHK];   // SoA: 4B random LDS writes (fewer bank conflicts)
    __shared__ unsigned biny[CHK];
    int tid = threadIdx.x;
    int blk = blockIdx.x;
    lcnt[tid] = 0; lcnt[tid + 256] = 0;
    __syncthreads();
    int e0 = blk * CHK;
    int nloc = min(CHK, E - e0);
    // pass 1: geometry into registers + bucket counts
    uint2 ent[CHK / SCT];
    int bkt[CHK / SCT];
    #pragma unroll
    for (int k = 0; k < CHK / SCT; ++k) {
        int i = k * SCT + tid;
        bkt[k] = -1;
        if (i < nloc) {
            int e = e0 + i;
            int s = esrc[e], d = edst[e];
            float vx = pos[s * 3 + 0] - pos[d * 3 + 0];
            float vy = pos[s * 3 + 1] - pos[d * 3 + 1];
            float vz = pos[s * 3 + 2] - pos[d * 3 + 2];
            float r = sqrtf(vx * vx + vy * vy + vz * vz);
            unsigned rtfix = (unsigned)fminf(r * (65535.0f / RMAXF) + 0.5f, 65535.0f);
            ent[k].x = (unsigned)s | (rtfix << 16);
            ent[k].y = (unsigned)d;
            bkt[k] = d >> 7;
            atomicAdd(&lcnt[bkt[k]], 1);
        }
    }
    __syncthreads();
    // inclusive scan of lcnt over 512 entries, 2 per thread
    lcur[tid] = lcnt[tid];
    lcur[tid + 256] = lcnt[tid + 256];
    __syncthreads();
    for (int off = 1; off < 512; off <<= 1) {
        int v0 = (tid >= off) ? lcur[tid - off] : 0;
        int v1 = (tid + 256 >= off) ? lcur[tid + 256 - off] : 0;
        __syncthreads();
        if (tid >= off) lcur[tid] += v0;
        if (tid + 256 >= off) lcur[tid + 256] += v1;
        __syncthreads();
    }
    #pragma unroll
    for (int q = 0; q < 2; ++q) {
        int b = q * 256 + tid;
        int ex = lcur[b] - lcnt[b];    // exclusive local offset
        delta[b] = ((b < nbuck) ? bofs[(size_t)blk * nbuck + b] : 0) - ex;
        lcnt[b] = ex;                  // reuse lcnt as placement cursor
    }
    __syncthreads();
    // pass 2: place entries into LDS bins
    #pragma unroll
    for (int k = 0; k < CHK / SCT; ++k) {
        if (bkt[k] >= 0) {
            int slot = atomicAdd(&lcnt[bkt[k]], 1);
            binx[slot] = ent[k].x;
            biny[slot] = ent[k].y;
        }
    }
    __syncthreads();
    // pass 3: coalesced write-out (consecutive i in a bucket run -> consecutive global addr)
    #pragma unroll
    for (int k = 0; k < CHK / SCT; ++k) {
        int i = k * SCT + tid;
        if (i < nloc) {
            uint2 v;
            v.x = binx[i];
            v.y = biny[i];
            int b = ((int)v.y) >> 7;
            bbuf[delta[b] + i] = v;
        }
    }
}

// ---------------- phase 2: bucket counting-sort -> padded CSR(4B) + rowinfo + padfill ----------------
__global__ void k_scat2(const uint2* __restrict__ bbuf, const int* __restrict__ bbase,
                        unsigned* __restrict__ csr, int2* __restrict__ rowinfo, int N) {
    int b = blockIdx.x;
    int tid = threadIdx.x;
    __shared__ int cnt128[128];
    __shared__ int base128[128];
    __shared__ int cur[128];
    __shared__ int part[128];
    if (tid < 128) cnt128[tid] = 0;
    __syncthreads();
    int j0 = bbase[b], j1 = bbase[b + 1];
    int n0 = b << 7;
    for (int j = j0 + tid; j < j1; j += 256)
        atomicAdd(&cnt128[((int)bbuf[j].y) & 127], 1);
    __syncthreads();
    if (tid < 128) part[tid] = (cnt128[tid] + 3) & ~3;
    __syncthreads();
    for (int off = 1; off < 128; off <<= 1) {
        int v = 0;
        if (tid < 128 && tid >= off) v = part[tid - off];
        __syncthreads();
        if (tid < 128) part[tid] += v;
        __syncthreads();
    }
    int pbase = j0 + 512 * b;   // padded base: bbase[b] + per-bucket pad slack
    if (tid < 128) {
        int ex = pbase + ((tid == 0) ? 0 : part[tid - 1]);
        base128[tid] = ex;
        cur[tid] = ex;
        int n = n0 + tid;
        if (n < N) rowinfo[n] = make_int2(ex, (cnt128[tid] + 3) & ~3);
    }
    __syncthreads();
    for (int j = j0 + tid; j < j1; j += 256) {
        uint2 e = bbuf[j];
        int local = ((int)e.y) & 127;
        int slot = atomicAdd(&cur[local], 1);
        csr[slot] = e.x;
    }
    __syncthreads();
    // sentinel padfill (<=3 per node): rtfix=0xFFFF -> table row 4095 = zeros
    if (tid < 128) {
        int end = base128[tid] + ((cnt128[tid] + 3) & ~3);
        for (int s = cur[tid]; s < end; ++s) csr[s] = 0xFFFF0000u;
    }
}

// ---------------- fused aggregation + node update; 4 nodes/wave, one DMA drain ----------------
__launch_bounds__(256)
__global__ void k_aggupd(const int2* __restrict__ rowinfo,
                         const unsigned* __restrict__ csr,
                         const __half* __restrict__ tbh, const __half* __restrict__ p0g,
                         const float* __restrict__ x0c,
                         float* __restrict__ x0n, __half* __restrict__ p0out,
                         const float* __restrict__ Wsc, const float* __restrict__ Wa,
                         const float* __restrict__ P0n,
                         int N, int wp0) {
    const float INVS = 0.17677669529663687f;  // 1/sqrt(32)
    __shared__ unsigned ROW[4][4][96];   // 4 nodes/wave, 64-edge window + prefetch slack
    int tid = threadIdx.x;
    int wid = tid >> 6;
    int lane = tid & 63;
    int n0 = blockIdx.x * 16 + wid * 4;
    if (n0 >= N) return;
    int g = lane >> 4, c = lane & 15;
    // rowinfo for the 4-aligned quad as two 16B loads
    int4 rA = ((const int4*)rowinfo)[n0 >> 1];
    int4 rB = ((const int4*)rowinfo)[(n0 >> 1) + 1];
    int e0s[4] = {rA.x, rA.z, rB.x, rB.z};
    int pls[4] = {rA.y, rA.w, rB.y, rB.w};
    #pragma unroll
    for (int i = 0; i < 4; ++i) if (n0 + i >= N) pls[i] = 0;
    // issue all DMAs, one drain
    #pragma unroll
    for (int i = 0; i < 4; ++i) {
        if (pls[i] > 0)
            __builtin_amdgcn_global_load_lds(
                (const __attribute__((address_space(1))) void*)(csr + e0s[i] + lane),
                (__attribute__((address_space(3))) void*)(&ROW[wid][i][0]), 4, 0, 0);
    }
    // x0 rows for all nodes (issued before the drain to overlap)
    float xr[4] = {0, 0, 0, 0};
    if (lane < 16) {
        #pragma unroll
        for (int i = 0; i < 4; ++i)
            if (n0 + i < N) xr[i] = x0c[(size_t)(n0 + i) * 16 + lane];
    }
    asm volatile("s_waitcnt vmcnt(0)" ::: "memory");
    #pragma unroll
    for (int i = 0; i < 4; ++i) {
        int n = n0 + i;
        if (n >= N) break;
        int e0 = e0s[i];
        int plen = pls[i];
        float xr0 = xr[i];
        float a0 = 0.0f;
        if (plen > 0) {
            const unsigned* RB = &ROW[wid][i][0];
            int L = plen >> 2;               // pad-4 rows: exact group count
            int Lm = L < 16 ? L : 16;        // LDS window covers 64 edges
            unsigned c0 = RB[g], c1 = RB[4 + g], c2v = RB[8 + g], c3 = RB[12 + g];
            float p0v = __half2float(p0g[(c0 & 0xffffu) * 16 + c]);
            float w0v = __half2float(tbh[(c0 >> 20) * 16 + c]);
            float p1v = __half2float(p0g[(c1 & 0xffffu) * 16 + c]);
            float w1v = __half2float(tbh[(c1 >> 20) * 16 + c]);
            float p2v = __half2float(p0g[(c2v & 0xffffu) * 16 + c]);
            float w2v = __half2float(tbh[(c2v >> 20) * 16 + c]);
            float p3v = __half2float(p0g[(c3 & 0xffffu) * 16 + c]);
            float w3v = __half2float(tbh[(c3 >> 20) * 16 + c]);
            #pragma unroll 2
            for (int k = 0; k < Lm; ++k) {
                unsigned c4 = RB[(k + 4) * 4 + g];      // max idx 91 < 96
                float p4v = __half2float(p0g[(c4 & 0xffffu) * 16 + c]);
                float w4v = __half2float(tbh[(c4 >> 20) * 16 + c]);
                a0 += w0v * p0v;
                c0 = c1; c1 = c2v; c2v = c3; c3 = c4;
                p0v = p1v; w0v = w1v;
                p1v = p2v; w1v = w2v;
                p2v = p3v; w2v = w3v;
                p3v = p4v; w3v = w4v;
            }
            if (plen > 64) {   // rare fallback beyond LDS window (Poisson(32): ~never)
                for (int j = e0 + 64 + g; j < e0 + plen; j += 4) {
                    unsigned cx = csr[j];
                    a0 += __half2float(tbh[(cx >> 20) * 16 + c]) *
                          __half2float(p0g[(cx & 0xffffu) * 16 + c]);
                }
            }
        }
        // reduce over the 4 edge slots (lane bits 4,5); lane&15 = channel
        a0 += __shfl_xor(a0, 16);
        a0 += __shfl_xor(a0, 32);
        a0 *= INVS;
        // tail: s_j = sum_cc x0[cc]*Wsc[cc*48+j] + agg0[cc]*Wa[cc*48+j]; split cc over 4 slots
        float sj = 0.0f;
        #pragma unroll
        for (int t = 0; t < 4; ++t) {
            int cc = g * 4 + t;
            float xv = __shfl(xr0, cc);
            float av = __shfl(a0, cc);
            sj += xv * Wsc[cc * 48 + c] + av * Wa[cc * 48 + c];
        }
        sj += __shfl_xor(sj, 16);
        sj += __shfl_xor(sj, 32);
        float act = sj * sigmoidf_(sj);
        if (lane < 16) x0n[(size_t)n * 16 + lane] = act;
        // p0 for next layer
        if (wp0) {
            float pn = 0.0f;
            #pragma unroll
            for (int t = 0; t < 4; ++t) {
                int cc = g * 4 + t;
                float av = __shfl(act, cc);
                pn += av * P0n[cc * 16 + c];
            }
            pn += __shfl_xor(pn, 16);
            pn += __shfl_xor(pn, 32);
            if (lane < 16) p0out[(size_t)n * 16 + lane] = __float2half(pn);
        }
    }
}

// ---------------- final reduction ----------------
__global__ void k_out1(const float* __restrict__ x0, const float* __restrict__ Wout,
                       float* __restrict__ partial, int N) {
    __shared__ float red[256];
    int tid = threadIdx.x;
    float s = 0.0f;
    for (int n = blockIdx.x * blockDim.x + tid; n < N; n += gridDim.x * blockDim.x) {
        float acc = 0.0f;
        #pragma unroll
        for (int cc = 0; cc < 16; ++cc) acc += x0[n * 16 + cc] * Wout[cc];
        s += acc;
    }
    red[tid] = s;
    __syncthreads();
    for (int off = 128; off > 0; off >>= 1) {
        if (tid < off) red[tid] += red[tid + off];
        __syncthreads();
    }
    if (tid == 0) partial[blockIdx.x] = red[0];
}

__global__ void k_out2(const float* __restrict__ partial, float* __restrict__ out,
                       int nb, float scale) {
    __shared__ float red[256];
    int tid = threadIdx.x;
    red[tid] = (tid < nb) ? partial[tid] : 0.0f;
    __syncthreads();
    for (int off = 128; off > 0; off >>= 1) {
        if (tid < off) red[tid] += red[tid + off];
        __syncthreads();
    }
    if (tid == 0) out[0] = red[0] * scale;
}

extern "C" void kernel_launch(void* const* d_in, const int* in_sizes, int n_in,
                              void* d_out, int out_size, void* d_ws, size_t ws_size,
                              hipStream_t stream) {
    const float* pos = (const float*)d_in[0];
    const float* x   = (const float*)d_in[1];
    const int* esrc  = (const int*)d_in[2];
    const int* edst  = (const int*)d_in[3];
    const float* mlp_w1 = (const float*)d_in[5];
    const float* mlp_b1 = (const float*)d_in[6];
    const float* mlp_w2 = (const float*)d_in[7];
    const float* P0  = (const float*)d_in[8];
    const float* Wsc = (const float*)d_in[9];
    const float* Wa  = (const float*)d_in[10];
    const float* Wout = (const float*)d_in[13];
    int N = in_sizes[0] / 3;
    int E = in_sizes[2];
    int nbuck = (N + 127) >> 7;
    int nblk = (E + CHK - 1) / CHK;
    int M = nbuck * nblk;
    int cap = E + 512 * nbuck + 256;
    int nscan = (M + 1023) / 1024;

    char* ws = (char*)d_ws;
    size_t off = 0;
    auto alloc = [&](size_t bytes) -> void* {
        void* p = ws + off;
        off += (bytes + 255) & ~(size_t)255;
        return p;
    };
    int2*     rowinfo   = (int2*)alloc((size_t)(N + 4) * 8);
    int*      bbase     = (int*)alloc(513 * 4);
    int*      bsum      = (int*)alloc(512 * 4);
    int*      bcnt      = (int*)alloc((size_t)M * 4);
    int*      bofs      = (int*)alloc((size_t)M * 4);
    unsigned* csr       = (unsigned*)alloc((size_t)cap * 4);
    __half*   tbh       = (__half*)alloc((size_t)3 * TSZ2 * 16 * 2);
    __half*   p0A = (__half*)alloc((size_t)65536 * 16 * 2);   // src is 16-bit: index-safe
    __half*   p0B = (__half*)alloc((size_t)65536 * 16 * 2);
    float*    x0A = (float*)alloc((size_t)N * 16 * 4);
    float*    x0B = (float*)alloc((size_t)N * 16 * 4);
    uint2*    bbuf = (uint2*)alloc((size_t)E * 8);
    float*    partial = (float*)alloc(256 * 4);

    k_hist<<<nblk + 3 * (TSZ2 / 32), 256, 0, stream>>>(edst, bcnt, E, nblk, nbuck, x, P0, p0A, N,
                                                       mlp_w1, mlp_b1, mlp_w2, tbh);
    k_scanA<<<nscan, 256, 0, stream>>>(bcnt, bsum, M);
    k_scanC<<<nscan, 256, 0, stream>>>(bcnt, bsum, bofs, bbase, M, nblk, nbuck, E);
    k_scat1<<<nblk, SCT, 0, stream>>>(pos, esrc, edst, bofs, bbuf, E, nbuck);
    k_scat2<<<nbuck, 256, 0, stream>>>(bbuf, bbase, csr, rowinfo, N);

    float* x0bufs[2] = {x0A, x0B};
    __half* p0bufs[2] = {p0A, p0B};
    for (int l = 0; l < 3; ++l) {
        const float* x0c = (l == 0) ? x : x0bufs[l & 1];
        float* x0n = x0bufs[(l & 1) ^ 1];
        const __half* p0c = p0bufs[l & 1];
        __half* p0n = p0bufs[(l & 1) ^ 1];
        const float* P0next = (l < 2) ? (P0 + (l + 1) * 256) : P0;
        k_aggupd<<<(N + 15) / 16, 256, 0, stream>>>(
            rowinfo, csr, tbh + (size_t)l * TSZ2 * 16, p0c,
            x0c, x0n, p0n,
            Wsc + l * 768, Wa + l * 768, P0next, N, (l < 2) ? 1 : 0);
    }
    float scale = (float)(1.0 / sqrt((double)N));
    k_out1<<<256, 256, 0, stream>>>(x0bufs[1], Wout, partial, N);
    k_out2<<<1, 256, 0, stream>>>(partial, (float*)d_out, 256, scale);
}